// Round 7
// baseline (153.898 us; speedup 1.0000x reference)
//
#include <hip/hip_runtime.h>
#include <math.h>

constexpr int kB   = 16;
constexpr int kNL  = 4096;
constexpr int kNH  = 1024;
constexpr int kCL  = 128;
constexpr int kCH  = 256;
constexpr int kOUT = 256;

typedef __attribute__((ext_vector_type(8))) short s16x8;
typedef __attribute__((ext_vector_type(8))) unsigned short u16x8;
typedef __attribute__((ext_vector_type(4))) unsigned short u16x4;
typedef __attribute__((ext_vector_type(4))) float f32x4;

__device__ __forceinline__ unsigned short f2bf(float x) {
    unsigned int u = __float_as_uint(x);
    return (unsigned short)((u + 0x7FFFu + ((u >> 16) & 1u)) >> 16);
}
__device__ __forceinline__ unsigned int f2bf_pk(float a, float b) {
    return (unsigned int)f2bf(a) | ((unsigned int)f2bf(b) << 16);
}
__device__ __forceinline__ float bf2f(unsigned short h) {
    return __uint_as_float((unsigned int)h << 16);
}

// ---------------------------------------------------------------------------
// W (256x384 f32) -> W1bf (256x256 bf16), W2bf (256x128 bf16)
// ---------------------------------------------------------------------------
__global__ void k_prep_w(const float* __restrict__ W, unsigned short* __restrict__ w1,
                         unsigned short* __restrict__ w2) {
    int o = blockIdx.x, k = threadIdx.x;
    float v = W[o * 384 + k];
    if (k < kCH) w1[o * kCH + k] = f2bf(v);
    else         w2[o * kCL + (k - kCH)] = f2bf(v);
}

// ---------------------------------------------------------------------------
// cand[b][j] = {2x, 2y, 2z, x^2+y^2+z^2}; pre-doubling is fp-exact.
// ---------------------------------------------------------------------------
__global__ void k_prep_cand(const float* __restrict__ xyzh, float4* __restrict__ cand) {
    int b = blockIdx.x;
    const float* H = xyzh + (size_t)b * kNH * 3;
    for (int j = threadIdx.x; j < kNH; j += 256) {
        float xx = H[j * 3 + 0], yy = H[j * 3 + 1], zz = H[j * 3 + 2];
        float s = __fmul_rn(xx, xx);
        s = __fadd_rn(s, __fmul_rn(yy, yy));
        s = __fadd_rn(s, __fmul_rn(zz, zz));
        cand[(size_t)b * kNH + j] = make_float4(xx + xx, yy + yy, zz + zz, s);
    }
}

// ---------------------------------------------------------------------------
// GEMM1: G = W1 x feat_high per batch, 32-col tiles (grid 512 = 2 blocks/CU).
// Reads fhigh f32 directly, converts to bf16 while staging into LDS.
// Output gtb bf16 in fragment-permuted layout [w][hi][mi][r].
// ---------------------------------------------------------------------------
__global__ __launch_bounds__(256, 4) void k_gemm1(
    const float* __restrict__ fhigh, const unsigned short* __restrict__ w1,
    unsigned short* __restrict__ gtb)
{
    __shared__ __align__(16) unsigned short Bt[32][264];
    int b = blockIdx.y, j0 = blockIdx.x * 32, t = threadIdx.x;
    const float* src = fhigh + (size_t)b * kCH * kNH + j0;
    // 128 c-pairs x 8 j4-groups, 4 units/thread
    #pragma unroll
    for (int i = 0; i < 4; ++i) {
        int e = t + i * 256, cp = e >> 3, j4 = e & 7;
        f32x4 a  = *(const f32x4*)(src + (size_t)(2 * cp)     * kNH + 4 * j4);
        f32x4 b2 = *(const f32x4*)(src + (size_t)(2 * cp + 1) * kNH + 4 * j4);
        #pragma unroll
        for (int r = 0; r < 4; ++r)
            *(unsigned int*)(&Bt[4 * j4 + r][2 * cp]) = f2bf_pk(a[r], b2[r]);
    }
    __syncthreads();

    int w = t >> 6, lane = t & 63, lo = lane & 15, hi = lane >> 4;
    f32x4 vz = {0.f, 0.f, 0.f, 0.f};
    f32x4 acc[4][2];
    #pragma unroll
    for (int mi = 0; mi < 4; ++mi)
        #pragma unroll
        for (int ni = 0; ni < 2; ++ni) acc[mi][ni] = vz;

    #pragma unroll
    for (int ks = 0; ks < 8; ++ks) {
        s16x8 av[4], bv[2];
        #pragma unroll
        for (int mi = 0; mi < 4; ++mi)
            av[mi] = *(const s16x8*)(w1 + (size_t)(64 * w + 16 * mi + lo) * kCH + ks * 32 + hi * 8);
        #pragma unroll
        for (int ni = 0; ni < 2; ++ni)
            bv[ni] = *(const s16x8*)(&Bt[16 * ni + lo][ks * 32 + hi * 8]);
        #pragma unroll
        for (int mi = 0; mi < 4; ++mi)
            #pragma unroll
            for (int ni = 0; ni < 2; ++ni)
                acc[mi][ni] = __builtin_amdgcn_mfma_f32_16x16x32_bf16(av[mi], bv[ni], acc[mi][ni], 0, 0, 0);
    }

    unsigned short* G = gtb + ((size_t)b * kNH + j0) * kOUT;
    #pragma unroll
    for (int mi = 0; mi < 4; ++mi)
        #pragma unroll
        for (int ni = 0; ni < 2; ++ni) {
            f32x4 a = acc[mi][ni];
            u16x4 h;
            #pragma unroll
            for (int r = 0; r < 4; ++r) h[r] = f2bf(a[r]);
            *(u16x4*)(&G[(size_t)(16 * ni + lo) * kOUT + w * 64 + hi * 16 + mi * 4]) = h;
        }
}

// ---------------------------------------------------------------------------
// FUSED: three_nn + GEMM2 + interp-gather + bias + partial BN stats.
// 32-col blocks (grid 2048 = 8/CU), LDS ~18 KB, VGPR<=64 -> up to 32 waves/CU.
// LDS liveness: {Bt, md, midx} live in the nn/kloop phase; red (stats table)
// only after the post-gather barrier -> all share one 17408-B region.
// ---------------------------------------------------------------------------
__global__ __launch_bounds__(256, 8) void k_gemm2(
    const float* __restrict__ flow, const unsigned short* __restrict__ w2,
    const unsigned short* __restrict__ gtb, const float* __restrict__ bias,
    const float* __restrict__ xyzl, const float4* __restrict__ cand,
    unsigned short* __restrict__ ybf, float* __restrict__ ps, float* __restrict__ pq)
{
    __shared__ __align__(16) char smem[17408];
    unsigned short (*Bt)[136] = (unsigned short (*)[136])smem;   // [32][136] = 8704 B
    float* mdp = (float*)(smem + 8704);                          // [32][8][3] = 3072 B
    int*   mip = (int*)(smem + 11776);                           // [32][8][3] = 3072 B
    float* red = (float*)smem;                                   // [256][17] = 17408 B
    __shared__ float wc[32][3];
    __shared__ int   ic[32][3];

    int b = blockIdx.y, n0 = blockIdx.x * 32, t = threadIdx.x;
    int blin = b * gridDim.x + blockIdx.x;                       // 0..2047

    // --- stage feat_low tile (f32 -> packed bf16) into Bt ---
    const float* src = flow + (size_t)b * kCL * kNL + n0;
    #pragma unroll
    for (int i = 0; i < 2; ++i) {
        int e = t + i * 256, cp = e >> 3, n4 = e & 7;
        f32x4 a  = *(const f32x4*)(src + (size_t)(2 * cp)     * kNL + 4 * n4);
        f32x4 b2 = *(const f32x4*)(src + (size_t)(2 * cp + 1) * kNL + 4 * n4);
        #pragma unroll
        for (int r = 0; r < 4; ++r)
            *(unsigned int*)(&Bt[4 * n4 + r][2 * cp]) = f2bf_pk(a[r], b2[r]);
    }
    __syncthreads();

    int w = t >> 6, lane = t & 63, lo = lane & 15, hi = lane >> 4;
    f32x4 vz = {0.f, 0.f, 0.f, 0.f};
    f32x4 acc[4][2];
    #pragma unroll
    for (int mi = 0; mi < 4; ++mi)
        #pragma unroll
        for (int ni = 0; ni < 2; ++ni) acc[mi][ni] = vz;

    // --- nn-scan: 32 points, 8 j-subranges each (sub = t>>5), 2 ILP streams ---
    auto do_nn = [&]() {
        int sub = t >> 5, ll = t & 31;
        int l = n0 + ll;
        const float* L = xyzl + ((size_t)b * kNL + l) * 3;
        float x = L[0], y = L[1], z = L[2];
        float sql = __fmul_rn(x, x);
        sql = __fadd_rn(sql, __fmul_rn(y, y));
        sql = __fadd_rn(sql, __fmul_rn(z, z));

        float dA0 = 1e30f, dA1 = 1e30f, dA2 = 1e30f;
        int   iA0 = 0,     iA1 = 0,     iA2 = 0;
        float dB0 = 1e30f, dB1 = 1e30f, dB2 = 1e30f;
        int   iB0 = 0,     iB1 = 0,     iB2 = 0;

        int jbeg = sub << 7;                       // 128 candidates per sub
        const float4* C = cand + ((size_t)b << 10) + jbeg;

        #pragma unroll 4
        for (int jj = 0; jj < 64; ++jj) {
            {   // stream A: [jbeg, jbeg+64)
                float4 c = C[jj];
                float inner2 = __fmul_rn(x, c.x);
                inner2 = __fadd_rn(inner2, __fmul_rn(y, c.y));
                inner2 = __fadd_rn(inner2, __fmul_rn(z, c.z));
                float dsq = __fsub_rn(__fadd_rn(sql, c.w), inner2);
                dsq = fmaxf(dsq, 0.0f);
                int j = jbeg + jj;
                bool c0 = dsq < dA0, c1 = dsq < dA1, c2 = dsq < dA2;
                float td = c1 ? dA1 : dsq;  int ti = c1 ? iA1 : j;
                dA2 = c2 ? td : dA2;        iA2 = c2 ? ti : iA2;
                td = c0 ? dA0 : dsq;        ti = c0 ? iA0 : j;
                dA1 = c1 ? td : dA1;        iA1 = c1 ? ti : iA1;
                dA0 = c0 ? dsq : dA0;       iA0 = c0 ? j : iA0;
            }
            {   // stream B: [jbeg+64, jbeg+128)
                float4 c = C[64 + jj];
                float inner2 = __fmul_rn(x, c.x);
                inner2 = __fadd_rn(inner2, __fmul_rn(y, c.y));
                inner2 = __fadd_rn(inner2, __fmul_rn(z, c.z));
                float dsq = __fsub_rn(__fadd_rn(sql, c.w), inner2);
                dsq = fmaxf(dsq, 0.0f);
                int j = jbeg + 64 + jj;
                bool c0 = dsq < dB0, c1 = dsq < dB1, c2 = dsq < dB2;
                float td = c1 ? dB1 : dsq;  int ti = c1 ? iB1 : j;
                dB2 = c2 ? td : dB2;        iB2 = c2 ? ti : iB2;
                td = c0 ? dB0 : dsq;        ti = c0 ? iB0 : j;
                dB1 = c1 ? td : dB1;        iB1 = c1 ? ti : iB1;
                dB0 = c0 ? dsq : dB0;       iB0 = c0 ? j : iB0;
            }
        }

        // merge stream B into A, lex (d, idx) = top_k tie semantics
        #pragma unroll
        for (int m = 0; m < 3; ++m) {
            float d = (m == 0) ? dB0 : (m == 1) ? dB1 : dB2;
            int  ii = (m == 0) ? iB0 : (m == 1) ? iB1 : iB2;
            bool lt2 = (d < dA2) || (d == dA2 && ii < iA2);
            if (lt2) {
                bool lt0 = (d < dA0) || (d == dA0 && ii < iA0);
                bool lt1 = (d < dA1) || (d == dA1 && ii < iA1);
                if (lt0)      { dA2 = dA1; iA2 = iA1; dA1 = dA0; iA1 = iA0; dA0 = d; iA0 = ii; }
                else if (lt1) { dA2 = dA1; iA2 = iA1; dA1 = d; iA1 = ii; }
                else          { dA2 = d; iA2 = ii; }
            }
        }

        int mo = (ll * 8 + sub) * 3;
        mdp[mo + 0] = dA0;  mdp[mo + 1] = dA1;  mdp[mo + 2] = dA2;
        mip[mo + 0] = iA0;  mip[mo + 1] = iA1;  mip[mo + 2] = iA2;
        __syncthreads();

        if (sub == 0) {
            float e0 = 1e30f, e1 = 1e30f, e2 = 1e30f;
            int   a0 = 0x7fffffff, a1 = 0x7fffffff, a2 = 0x7fffffff;
            #pragma unroll
            for (int s = 0; s < 8; ++s) {
                #pragma unroll
                for (int k = 0; k < 3; ++k) {
                    float d = mdp[(ll * 8 + s) * 3 + k];
                    int  ii = mip[(ll * 8 + s) * 3 + k];
                    bool lt2 = (d < e2) || (d == e2 && ii < a2);
                    if (lt2) {
                        bool lt0 = (d < e0) || (d == e0 && ii < a0);
                        bool lt1 = (d < e1) || (d == e1 && ii < a1);
                        if (lt0)      { e2 = e1; a2 = a1; e1 = e0; a1 = a0; e0 = d; a0 = ii; }
                        else if (lt1) { e2 = e1; a2 = a1; e1 = d; a1 = ii; }
                        else          { e2 = d; a2 = ii; }
                    }
                }
            }
            float q0 = fmaxf(sqrtf(e0), 1e-8f);
            float q1 = fmaxf(sqrtf(e1), 1e-8f);
            float q2 = fmaxf(sqrtf(e2), 1e-8f);
            float r0 = 1.0f / q0, r1 = 1.0f / q1, r2 = 1.0f / q2;
            float s = __fadd_rn(__fadd_rn(r0, r1), r2);
            wc[ll][0] = r0 / s;  wc[ll][1] = r1 / s;  wc[ll][2] = r2 / s;
            ic[ll][0] = a0;      ic[ll][1] = a1;      ic[ll][2] = a2;
        }
    };

    // --- MFMA K-loop: y += W2 x feat_low_tile ---
    auto do_kloop = [&]() {
        #pragma unroll
        for (int ks = 0; ks < 4; ++ks) {
            s16x8 av[4], bv[2];
            #pragma unroll
            for (int mi = 0; mi < 4; ++mi)
                av[mi] = *(const s16x8*)(w2 + (size_t)(64 * w + 16 * mi + lo) * kCL + ks * 32 + hi * 8);
            #pragma unroll
            for (int ni = 0; ni < 2; ++ni)
                bv[ni] = *(const s16x8*)(&Bt[16 * ni + lo][ks * 32 + hi * 8]);
            #pragma unroll
            for (int mi = 0; mi < 4; ++mi)
                #pragma unroll
                for (int ni = 0; ni < 2; ++ni)
                    acc[mi][ni] = __builtin_amdgcn_mfma_f32_16x16x32_bf16(av[mi], bv[ni], acc[mi][ni], 0, 0, 0);
        }
    };

    // phase stagger across blocks
    if (blockIdx.x & 1) { do_kloop(); do_nn(); }
    else                { do_nn();    do_kloop(); }
    __syncthreads();   // wc/ic visible; Bt/md/midx dead after this point

    // --- gather: per neighbor k, stage loads in registers, then FMA ---
    const unsigned short* Gb = gtb + (size_t)b * kNH * kOUT + w * 64 + hi * 16;
    #pragma unroll
    for (int k = 0; k < 3; ++k) {
        u16x8 g0[2], g1[2];
        float wcr[2];
        #pragma unroll
        for (int ni = 0; ni < 2; ++ni) {
            int lc = 16 * ni + lo;
            int jj = ic[lc][k];
            wcr[ni] = wc[lc][k];
            const u16x8* p = (const u16x8*)(Gb + (size_t)jj * kOUT);
            g0[ni] = p[0];
            g1[ni] = p[1];
        }
        #pragma unroll
        for (int ni = 0; ni < 2; ++ni) {
            float wg = wcr[ni];
            #pragma unroll
            for (int r = 0; r < 4; ++r) {
                acc[0][ni][r] = fmaf(wg, bf2f(g0[ni][r]),     acc[0][ni][r]);
                acc[1][ni][r] = fmaf(wg, bf2f(g0[ni][4 + r]), acc[1][ni][r]);
                acc[2][ni][r] = fmaf(wg, bf2f(g1[ni][r]),     acc[2][ni][r]);
                acc[3][ni][r] = fmaf(wg, bf2f(g1[ni][4 + r]), acc[3][ni][r]);
            }
        }
    }
    #pragma unroll
    for (int mi = 0; mi < 4; ++mi) {
        f32x4 bb = *(const f32x4*)(bias + 64 * w + 16 * mi + 4 * hi);
        #pragma unroll
        for (int ni = 0; ni < 2; ++ni) acc[mi][ni] += bb;
    }

    // store y (bf16)
    unsigned short* Y = ybf + (size_t)b * kOUT * kNL + n0;
    #pragma unroll
    for (int mi = 0; mi < 4; ++mi)
        #pragma unroll
        for (int ni = 0; ni < 2; ++ni)
            #pragma unroll
            for (int r = 0; r < 4; ++r)
                Y[(size_t)(64 * w + 16 * mi + 4 * hi + r) * kNL + 16 * ni + lo] = f2bf(acc[mi][ni][r]);

    // fused partial BN stats (from f32 accs), two rounds through red table
    int ow = t >> 6, omi = (t >> 4) & 3, ohi = (t >> 2) & 3, orr = t & 3;
    __syncthreads();   // Bt/md/midx dead -> red
    #pragma unroll
    for (int mi = 0; mi < 4; ++mi) {
        f32x4 s = acc[mi][0] + acc[mi][1];
        #pragma unroll
        for (int r = 0; r < 4; ++r) red[t * 17 + mi * 4 + r] = s[r];
    }
    __syncthreads();
    float ssum = 0.0f;
    #pragma unroll
    for (int l2 = 0; l2 < 16; ++l2)
        ssum += red[(ow * 64 + ohi * 16 + l2) * 17 + omi * 4 + orr];
    __syncthreads();
    #pragma unroll
    for (int mi = 0; mi < 4; ++mi) {
        f32x4 q = acc[mi][0] * acc[mi][0] + acc[mi][1] * acc[mi][1];
        #pragma unroll
        for (int r = 0; r < 4; ++r) red[t * 17 + mi * 4 + r] = q[r];
    }
    __syncthreads();
    float qsum = 0.0f;
    #pragma unroll
    for (int l2 = 0; l2 < 16; ++l2)
        qsum += red[(ow * 64 + ohi * 16 + l2) * 17 + omi * 4 + orr];

    ps[(size_t)t * 2048 + blin] = ssum;
    pq[(size_t)t * 2048 + blin] = qsum;
}

// ---------------------------------------------------------------------------
__global__ void k_finalize(const float* __restrict__ ps, const float* __restrict__ pq,
                           const float* __restrict__ gamma, const float* __restrict__ beta,
                           float* __restrict__ cA, float* __restrict__ cB) {
    int o = blockIdx.x, t = threadIdx.x;
    float s = 0.0f, q = 0.0f;
    #pragma unroll
    for (int i = 0; i < 8; ++i) {
        s += ps[(size_t)o * 2048 + t + i * 256];
        q += pq[(size_t)o * 2048 + t + i * 256];
    }
    #pragma unroll
    for (int off = 32; off > 0; off >>= 1) {
        s += __shfl_down(s, off);
        q += __shfl_down(q, off);
    }
    __shared__ float ls[4], lq[4];
    if ((t & 63) == 0) { ls[t >> 6] = s; lq[t >> 6] = q; }
    __syncthreads();
    if (t == 0) {
        s = ls[0] + ls[1] + ls[2] + ls[3];
        q = lq[0] + lq[1] + lq[2] + lq[3];
        const float inv = 1.0f / (float)(kB * kNL);
        float mean = s * inv;
        float var  = q * inv - mean * mean;
        float a = gamma[o] * rsqrtf(var + 1e-5f);
        cA[o] = a;
        cB[o] = beta[o] - mean * a;
    }
}

// ---------------------------------------------------------------------------
// apply: read bf16 y (32 MB), write normalized+ReLU f32 out (64 MB)
// ---------------------------------------------------------------------------
__global__ void k_apply(const unsigned short* __restrict__ ybf, float* __restrict__ out,
                        const float* __restrict__ cA, const float* __restrict__ cB) {
    size_t idx    = (size_t)blockIdx.x * 256 + threadIdx.x;
    size_t stride = (size_t)gridDim.x * 256;
    const size_t n8 = (size_t)kB * kOUT * kNL / 8;
    const u16x8* yp = (const u16x8*)ybf;
    float4* op = (float4*)out;
    for (size_t i = idx; i < n8; i += stride) {
        int o = (int)((i >> 9) & 255);   // 512 u16x8 per (b,o) row
        float a = cA[o], c = cB[o];
        u16x8 v = yp[i];
        float4 r0, r1;
        r0.x = fmaxf(fmaf(a, bf2f(v[0]), c), 0.0f);
        r0.y = fmaxf(fmaf(a, bf2f(v[1]), c), 0.0f);
        r0.z = fmaxf(fmaf(a, bf2f(v[2]), c), 0.0f);
        r0.w = fmaxf(fmaf(a, bf2f(v[3]), c), 0.0f);
        r1.x = fmaxf(fmaf(a, bf2f(v[4]), c), 0.0f);
        r1.y = fmaxf(fmaf(a, bf2f(v[5]), c), 0.0f);
        r1.z = fmaxf(fmaf(a, bf2f(v[6]), c), 0.0f);
        r1.w = fmaxf(fmaf(a, bf2f(v[7]), c), 0.0f);
        op[2 * i]     = r0;
        op[2 * i + 1] = r1;
    }
}

// ---------------------------------------------------------------------------
extern "C" void kernel_launch(void* const* d_in, const int* in_sizes, int n_in,
                              void* d_out, int out_size, void* d_ws, size_t ws_size,
                              hipStream_t stream) {
    const float* xyzl  = (const float*)d_in[0];
    const float* xyzh  = (const float*)d_in[1];
    const float* flow  = (const float*)d_in[2];
    const float* fhigh = (const float*)d_in[3];
    const float* W     = (const float*)d_in[4];
    const float* bias  = (const float*)d_in[5];
    const float* gamma = (const float*)d_in[6];
    const float* beta  = (const float*)d_in[7];
    float* out = (float*)d_out;
    char*  ws  = (char*)d_ws;
    (void)in_sizes; (void)n_in; (void)out_size; (void)ws_size;

    // ws layout (bytes), total ~46.6 MB
    unsigned short* gtb  = (unsigned short*)(ws + 0);          // 8 MB (bf16, permuted)
    unsigned short* ybf  = (unsigned short*)(ws + 8388608);    // 32 MB (bf16 y)
    unsigned short* w1   = (unsigned short*)(ws + 41943040);   // 128 KB
    unsigned short* w2   = (unsigned short*)(ws + 42074112);   // 64 KB
    float*          ps   = (float*)(ws + 42139648);            // 2 MB
    float*          pq   = (float*)(ws + 44236800);            // 2 MB
    float*          cA   = (float*)(ws + 46333952);            // 1 KB
    float*          cB   = (float*)(ws + 46334976);            // 1 KB
    float4*         cand = (float4*)(ws + 46336000);           // 256 KB

    hipLaunchKernelGGL(k_prep_w,    dim3(256),          dim3(384), 0, stream, W, w1, w2);
    hipLaunchKernelGGL(k_prep_cand, dim3(kB),           dim3(256), 0, stream, xyzh, cand);
    hipLaunchKernelGGL(k_gemm1,     dim3(kNH / 32, kB), dim3(256), 0, stream, fhigh, w1, gtb);
    hipLaunchKernelGGL(k_gemm2,     dim3(kNL / 32, kB), dim3(256), 0, stream,
                       flow, w2, gtb, bias, xyzl, cand, ybf, ps, pq);
    hipLaunchKernelGGL(k_finalize,  dim3(256),          dim3(256), 0, stream, ps, pq, gamma, beta, cA, cB);
    hipLaunchKernelGGL(k_apply,     dim3(2048),         dim3(256), 0, stream, ybf, out, cA, cB);
}

// Round 9
// 121.668 us; speedup vs baseline: 1.2649x; 1.2649x over previous
//
#include <hip/hip_runtime.h>
#include <math.h>

constexpr int kB   = 16;
constexpr int kNL  = 4096;
constexpr int kNH  = 1024;
constexpr int kCL  = 128;
constexpr int kCH  = 256;
constexpr int kOUT = 256;

typedef __attribute__((ext_vector_type(8))) short s16x8;
typedef __attribute__((ext_vector_type(8))) unsigned short u16x8;
typedef __attribute__((ext_vector_type(4))) unsigned short u16x4;
typedef __attribute__((ext_vector_type(4))) float f32x4;

__device__ __forceinline__ unsigned short f2bf(float x) {
    unsigned int u = __float_as_uint(x);
    return (unsigned short)((u + 0x7FFFu + ((u >> 16) & 1u)) >> 16);
}
__device__ __forceinline__ unsigned int f2bf_pk(float a, float b) {
    return (unsigned int)f2bf(a) | ((unsigned int)f2bf(b) << 16);
}
__device__ __forceinline__ float bf2f(unsigned short h) {
    return __uint_as_float((unsigned int)h << 16);
}

// ---------------------------------------------------------------------------
// W (256x384 f32) -> W1bf (256x256 bf16), W2bf (256x128 bf16)
// ---------------------------------------------------------------------------
__global__ void k_prep_w(const float* __restrict__ W, unsigned short* __restrict__ w1,
                         unsigned short* __restrict__ w2) {
    int o = blockIdx.x, k = threadIdx.x;
    float v = W[o * 384 + k];
    if (k < kCH) w1[o * kCH + k] = f2bf(v);
    else         w2[o * kCL + (k - kCH)] = f2bf(v);
}

// ---------------------------------------------------------------------------
// cand[b][j] = {2x, 2y, 2z, x^2+y^2+z^2}; pre-doubling is fp-exact.
// ---------------------------------------------------------------------------
__global__ void k_prep_cand(const float* __restrict__ xyzh, float4* __restrict__ cand) {
    int b = blockIdx.x;
    const float* H = xyzh + (size_t)b * kNH * 3;
    for (int j = threadIdx.x; j < kNH; j += 256) {
        float xx = H[j * 3 + 0], yy = H[j * 3 + 1], zz = H[j * 3 + 2];
        float s = __fmul_rn(xx, xx);
        s = __fadd_rn(s, __fmul_rn(yy, yy));
        s = __fadd_rn(s, __fmul_rn(zz, zz));
        cand[(size_t)b * kNH + j] = make_float4(xx + xx, yy + yy, zz + zz, s);
    }
}

// ---------------------------------------------------------------------------
// MEGA: 1280 blocks, two roles co-resident per CU so gemm1's memory phases
// overlap the scan's VALU wall.
//   bid % 5 == 0  (256 blocks): GEMM1 tile  (G = W1 x feat_high, 64 j-cols)
//   else          (1024 blocks): three_nn scan for 64 low points -> w3/idx3
// Scan selection arithmetic is byte-identical to rounds 4-6 (exact fp32,
// lex-(d,idx) merges = jax.lax.top_k tie semantics).
// ---------------------------------------------------------------------------
__global__ __launch_bounds__(256, 4) void k_mega(
    const float* __restrict__ fhigh, const unsigned short* __restrict__ w1,
    unsigned short* __restrict__ gtb,
    const float* __restrict__ xyzl, const float4* __restrict__ cand,
    float* __restrict__ w3, int* __restrict__ idx3)
{
    __shared__ __align__(16) char smem[33792];   // union: Bt[64][264]us | md+midx
    int bid = blockIdx.x, t = threadIdx.x;

    if (bid % 5 == 0) {
        // ------------------- GEMM1 role -------------------
        unsigned short (*Bt)[264] = (unsigned short (*)[264])smem;
        int g = bid / 5;                 // 0..255
        int b = g >> 4, j0 = (g & 15) * 64;
        const float* src = fhigh + (size_t)b * kCH * kNH + j0;
        #pragma unroll
        for (int i = 0; i < 8; ++i) {
            int e = t + i * 256, cp = e >> 4, j4 = e & 15;
            f32x4 a  = *(const f32x4*)(src + (size_t)(2 * cp)     * kNH + 4 * j4);
            f32x4 b2 = *(const f32x4*)(src + (size_t)(2 * cp + 1) * kNH + 4 * j4);
            #pragma unroll
            for (int r = 0; r < 4; ++r)
                *(unsigned int*)(&Bt[4 * j4 + r][2 * cp]) = f2bf_pk(a[r], b2[r]);
        }
        __syncthreads();

        int w = t >> 6, lane = t & 63, lo = lane & 15, hi = lane >> 4;
        f32x4 vz = {0.f, 0.f, 0.f, 0.f};
        f32x4 acc[4][4];
        #pragma unroll
        for (int mi = 0; mi < 4; ++mi)
            #pragma unroll
            for (int ni = 0; ni < 4; ++ni) acc[mi][ni] = vz;

        #pragma unroll
        for (int ks = 0; ks < 8; ++ks) {
            s16x8 av[4], bv[4];
            #pragma unroll
            for (int mi = 0; mi < 4; ++mi)
                av[mi] = *(const s16x8*)(w1 + (size_t)(64 * w + 16 * mi + lo) * kCH + ks * 32 + hi * 8);
            #pragma unroll
            for (int ni = 0; ni < 4; ++ni)
                bv[ni] = *(const s16x8*)(&Bt[16 * ni + lo][ks * 32 + hi * 8]);
            #pragma unroll
            for (int mi = 0; mi < 4; ++mi)
                #pragma unroll
                for (int ni = 0; ni < 4; ++ni)
                    acc[mi][ni] = __builtin_amdgcn_mfma_f32_16x16x32_bf16(av[mi], bv[ni], acc[mi][ni], 0, 0, 0);
        }

        unsigned short* G = gtb + ((size_t)b * kNH + j0) * kOUT;
        #pragma unroll
        for (int mi = 0; mi < 4; ++mi)
            #pragma unroll
            for (int ni = 0; ni < 4; ++ni) {
                f32x4 a = acc[mi][ni];
                u16x4 h;
                #pragma unroll
                for (int r = 0; r < 4; ++r) h[r] = f2bf(a[r]);
                *(u16x4*)(&G[(size_t)(16 * ni + lo) * kOUT + w * 64 + hi * 16 + mi * 4]) = h;
            }
    } else {
        // ------------------- SCAN role -------------------
        float* md  = (float*)smem;               // [64][4][3]
        int*   mip = (int*)(smem + 3072);        // [64][4][3]
        int s = bid - bid / 5 - 1;               // 0..1023
        int b = s >> 6, n0 = (s & 63) * 64;
        int sub = t >> 6, ll = t & 63;
        int l = n0 + ll;

        const float* L = xyzl + ((size_t)b * kNL + l) * 3;
        float x = L[0], y = L[1], z = L[2];
        float sql = __fmul_rn(x, x);
        sql = __fadd_rn(sql, __fmul_rn(y, y));
        sql = __fadd_rn(sql, __fmul_rn(z, z));

        float dA0 = 1e30f, dA1 = 1e30f, dA2 = 1e30f;
        int   iA0 = 0,     iA1 = 0,     iA2 = 0;
        float dB0 = 1e30f, dB1 = 1e30f, dB2 = 1e30f;
        int   iB0 = 0,     iB1 = 0,     iB2 = 0;

        int jbeg = __builtin_amdgcn_readfirstlane(sub << 8);
        const float4* C = cand + ((size_t)b << 10) + jbeg;

        #pragma unroll 4
        for (int jj = 0; jj < 128; ++jj) {
            {   // stream A: [jbeg, jbeg+128)
                float4 c = C[jj];
                float inner2 = __fmul_rn(x, c.x);
                inner2 = __fadd_rn(inner2, __fmul_rn(y, c.y));
                inner2 = __fadd_rn(inner2, __fmul_rn(z, c.z));
                float dsq = __fsub_rn(__fadd_rn(sql, c.w), inner2);
                dsq = fmaxf(dsq, 0.0f);
                int j = jbeg + jj;
                bool c0 = dsq < dA0, c1 = dsq < dA1, c2 = dsq < dA2;
                float td = c1 ? dA1 : dsq;  int ti = c1 ? iA1 : j;
                dA2 = c2 ? td : dA2;        iA2 = c2 ? ti : iA2;
                td = c0 ? dA0 : dsq;        ti = c0 ? iA0 : j;
                dA1 = c1 ? td : dA1;        iA1 = c1 ? ti : iA1;
                dA0 = c0 ? dsq : dA0;       iA0 = c0 ? j : iA0;
            }
            {   // stream B: [jbeg+128, jbeg+256)
                float4 c = C[128 + jj];
                float inner2 = __fmul_rn(x, c.x);
                inner2 = __fadd_rn(inner2, __fmul_rn(y, c.y));
                inner2 = __fadd_rn(inner2, __fmul_rn(z, c.z));
                float dsq = __fsub_rn(__fadd_rn(sql, c.w), inner2);
                dsq = fmaxf(dsq, 0.0f);
                int j = jbeg + 128 + jj;
                bool c0 = dsq < dB0, c1 = dsq < dB1, c2 = dsq < dB2;
                float td = c1 ? dB1 : dsq;  int ti = c1 ? iB1 : j;
                dB2 = c2 ? td : dB2;        iB2 = c2 ? ti : iB2;
                td = c0 ? dB0 : dsq;        ti = c0 ? iB0 : j;
                dB1 = c1 ? td : dB1;        iB1 = c1 ? ti : iB1;
                dB0 = c0 ? dsq : dB0;       iB0 = c0 ? j : iB0;
            }
        }

        // merge stream B into A (lex (d, idx))
        #pragma unroll
        for (int m = 0; m < 3; ++m) {
            float d = (m == 0) ? dB0 : (m == 1) ? dB1 : dB2;
            int  ii = (m == 0) ? iB0 : (m == 1) ? iB1 : iB2;
            bool lt2 = (d < dA2) || (d == dA2 && ii < iA2);
            if (lt2) {
                bool lt0 = (d < dA0) || (d == dA0 && ii < iA0);
                bool lt1 = (d < dA1) || (d == dA1 && ii < iA1);
                if (lt0)      { dA2 = dA1; iA2 = iA1; dA1 = dA0; iA1 = iA0; dA0 = d; iA0 = ii; }
                else if (lt1) { dA2 = dA1; iA2 = iA1; dA1 = d; iA1 = ii; }
                else          { dA2 = d; iA2 = ii; }
            }
        }

        int mo = (ll * 4 + sub) * 3;
        md[mo + 0] = dA0;  md[mo + 1] = dA1;  md[mo + 2] = dA2;
        mip[mo + 0] = iA0; mip[mo + 1] = iA1; mip[mo + 2] = iA2;
        __syncthreads();

        if (sub == 0) {
            float e0 = 1e30f, e1 = 1e30f, e2 = 1e30f;
            int   a0 = 0x7fffffff, a1 = 0x7fffffff, a2 = 0x7fffffff;
            #pragma unroll
            for (int ss = 0; ss < 4; ++ss) {
                #pragma unroll
                for (int k = 0; k < 3; ++k) {
                    float d = md[(ll * 4 + ss) * 3 + k];
                    int  ii = mip[(ll * 4 + ss) * 3 + k];
                    bool lt2 = (d < e2) || (d == e2 && ii < a2);
                    if (lt2) {
                        bool lt0 = (d < e0) || (d == e0 && ii < a0);
                        bool lt1 = (d < e1) || (d == e1 && ii < a1);
                        if (lt0)      { e2 = e1; a2 = a1; e1 = e0; a1 = a0; e0 = d; a0 = ii; }
                        else if (lt1) { e2 = e1; a2 = a1; e1 = d; a1 = ii; }
                        else          { e2 = d; a2 = ii; }
                    }
                }
            }
            float q0 = fmaxf(sqrtf(e0), 1e-8f);
            float q1 = fmaxf(sqrtf(e1), 1e-8f);
            float q2 = fmaxf(sqrtf(e2), 1e-8f);
            float r0 = 1.0f / q0, r1 = 1.0f / q1, r2 = 1.0f / q2;
            float sw = __fadd_rn(__fadd_rn(r0, r1), r2);
            size_t base = ((size_t)b * kNL + l) * 3;
            w3[base + 0] = r0 / sw;  w3[base + 1] = r1 / sw;  w3[base + 2] = r2 / sw;
            idx3[base + 0] = a0;     idx3[base + 1] = a1;     idx3[base + 2] = a2;
        }
    }
}

// ---------------------------------------------------------------------------
// GEMM2 (lean): reads wc/ic from ws, K-loop, batched gather, bias, bf16-y
// store, fused partial BN stats. Structure identical to round 6 minus nn.
// ---------------------------------------------------------------------------
__global__ __launch_bounds__(256, 4) void k_gemm2(
    const float* __restrict__ flow, const unsigned short* __restrict__ w2,
    const unsigned short* __restrict__ gtb, const float* __restrict__ bias,
    const float* __restrict__ w3, const int* __restrict__ idx3,
    unsigned short* __restrict__ ybf, float* __restrict__ ps, float* __restrict__ pq)
{
    __shared__ __align__(16) char smem[17408];             // union: Bt | red
    unsigned short (*Bt)[136] = (unsigned short (*)[136])smem;
    float* red = (float*)smem;                             // [256][17]
    __shared__ float wc[64][3];
    __shared__ int   ic[64][3];

    int b = blockIdx.y, n0 = blockIdx.x * 64, t = threadIdx.x;
    int blin = b * gridDim.x + blockIdx.x;                 // 0..1023

    if (t < 192) {
        int n = t / 3, k = t - n * 3;
        wc[n][k] = w3[((size_t)b * kNL + n0 + n) * 3 + k];
        ic[n][k] = idx3[((size_t)b * kNL + n0 + n) * 3 + k];
    }
    const float* src = flow + (size_t)b * kCL * kNL + n0;
    #pragma unroll
    for (int i = 0; i < 4; ++i) {
        int e = t + i * 256, cp = e >> 4, n4 = e & 15;
        f32x4 a  = *(const f32x4*)(src + (size_t)(2 * cp)     * kNL + 4 * n4);
        f32x4 b2 = *(const f32x4*)(src + (size_t)(2 * cp + 1) * kNL + 4 * n4);
        #pragma unroll
        for (int r = 0; r < 4; ++r)
            *(unsigned int*)(&Bt[4 * n4 + r][2 * cp]) = f2bf_pk(a[r], b2[r]);
    }
    __syncthreads();

    int w = t >> 6, lane = t & 63, lo = lane & 15, hi = lane >> 4;
    f32x4 vz = {0.f, 0.f, 0.f, 0.f};
    f32x4 acc[4][4];
    #pragma unroll
    for (int mi = 0; mi < 4; ++mi)
        #pragma unroll
        for (int ni = 0; ni < 4; ++ni) acc[mi][ni] = vz;

    #pragma unroll
    for (int ks = 0; ks < 4; ++ks) {
        s16x8 av[4], bv[4];
        #pragma unroll
        for (int mi = 0; mi < 4; ++mi)
            av[mi] = *(const s16x8*)(w2 + (size_t)(64 * w + 16 * mi + lo) * kCL + ks * 32 + hi * 8);
        #pragma unroll
        for (int ni = 0; ni < 4; ++ni)
            bv[ni] = *(const s16x8*)(&Bt[16 * ni + lo][ks * 32 + hi * 8]);
        #pragma unroll
        for (int mi = 0; mi < 4; ++mi)
            #pragma unroll
            for (int ni = 0; ni < 4; ++ni)
                acc[mi][ni] = __builtin_amdgcn_mfma_f32_16x16x32_bf16(av[mi], bv[ni], acc[mi][ni], 0, 0, 0);
    }

    // gather: per neighbor k, stage 8 loads in registers, then convert+FMA
    const unsigned short* Gb = gtb + (size_t)b * kNH * kOUT + w * 64 + hi * 16;
    #pragma unroll
    for (int k = 0; k < 3; ++k) {
        u16x8 g0[4], g1[4];
        float wcr[4];
        #pragma unroll
        for (int ni = 0; ni < 4; ++ni) {
            int lc = 16 * ni + lo;
            int jj = ic[lc][k];
            wcr[ni] = wc[lc][k];
            const u16x8* p = (const u16x8*)(Gb + (size_t)jj * kOUT);
            g0[ni] = p[0];
            g1[ni] = p[1];
        }
        #pragma unroll
        for (int ni = 0; ni < 4; ++ni) {
            float wg = wcr[ni];
            #pragma unroll
            for (int r = 0; r < 4; ++r) {
                acc[0][ni][r] = fmaf(wg, bf2f(g0[ni][r]),     acc[0][ni][r]);
                acc[1][ni][r] = fmaf(wg, bf2f(g0[ni][4 + r]), acc[1][ni][r]);
                acc[2][ni][r] = fmaf(wg, bf2f(g1[ni][r]),     acc[2][ni][r]);
                acc[3][ni][r] = fmaf(wg, bf2f(g1[ni][4 + r]), acc[3][ni][r]);
            }
        }
    }
    #pragma unroll
    for (int mi = 0; mi < 4; ++mi) {
        f32x4 bb = *(const f32x4*)(bias + 64 * w + 16 * mi + 4 * hi);
        #pragma unroll
        for (int ni = 0; ni < 4; ++ni) acc[mi][ni] += bb;
    }

    // store y (bf16)
    unsigned short* Y = ybf + (size_t)b * kOUT * kNL + n0;
    #pragma unroll
    for (int mi = 0; mi < 4; ++mi)
        #pragma unroll
        for (int ni = 0; ni < 4; ++ni)
            #pragma unroll
            for (int r = 0; r < 4; ++r)
                Y[(size_t)(64 * w + 16 * mi + 4 * hi + r) * kNL + 16 * ni + lo] = f2bf(acc[mi][ni][r]);

    // fused partial BN stats (from f32 accs), two rounds through red table
    int ow = t >> 6, omi = (t >> 4) & 3, ohi = (t >> 2) & 3, orr = t & 3;
    __syncthreads();   // Bt dead -> red
    #pragma unroll
    for (int mi = 0; mi < 4; ++mi) {
        f32x4 s = acc[mi][0] + acc[mi][1] + acc[mi][2] + acc[mi][3];
        #pragma unroll
        for (int r = 0; r < 4; ++r) red[t * 17 + mi * 4 + r] = s[r];
    }
    __syncthreads();
    float ssum = 0.0f;
    #pragma unroll
    for (int l2 = 0; l2 < 16; ++l2)
        ssum += red[(ow * 64 + ohi * 16 + l2) * 17 + omi * 4 + orr];
    __syncthreads();
    #pragma unroll
    for (int mi = 0; mi < 4; ++mi) {
        f32x4 q = acc[mi][0] * acc[mi][0] + acc[mi][1] * acc[mi][1]
                + acc[mi][2] * acc[mi][2] + acc[mi][3] * acc[mi][3];
        #pragma unroll
        for (int r = 0; r < 4; ++r) red[t * 17 + mi * 4 + r] = q[r];
    }
    __syncthreads();
    float qsum = 0.0f;
    #pragma unroll
    for (int l2 = 0; l2 < 16; ++l2)
        qsum += red[(ow * 64 + ohi * 16 + l2) * 17 + omi * 4 + orr];

    ps[(size_t)t * 1024 + blin] = ssum;
    pq[(size_t)t * 1024 + blin] = qsum;
}

// ---------------------------------------------------------------------------
__global__ void k_finalize(const float* __restrict__ ps, const float* __restrict__ pq,
                           const float* __restrict__ gamma, const float* __restrict__ beta,
                           float* __restrict__ cA, float* __restrict__ cB) {
    int o = blockIdx.x, t = threadIdx.x;
    float s = 0.0f, q = 0.0f;
    #pragma unroll
    for (int i = 0; i < 4; ++i) {
        s += ps[(size_t)o * 1024 + t + i * 256];
        q += pq[(size_t)o * 1024 + t + i * 256];
    }
    #pragma unroll
    for (int off = 32; off > 0; off >>= 1) {
        s += __shfl_down(s, off);
        q += __shfl_down(q, off);
    }
    __shared__ float ls[4], lq[4];
    if ((t & 63) == 0) { ls[t >> 6] = s; lq[t >> 6] = q; }
    __syncthreads();
    if (t == 0) {
        s = ls[0] + ls[1] + ls[2] + ls[3];
        q = lq[0] + lq[1] + lq[2] + lq[3];
        const float inv = 1.0f / (float)(kB * kNL);
        float mean = s * inv;
        float var  = q * inv - mean * mean;
        float a = gamma[o] * rsqrtf(var + 1e-5f);
        cA[o] = a;
        cB[o] = beta[o] - mean * a;
    }
}

// ---------------------------------------------------------------------------
// apply: read bf16 y (32 MB), write normalized+ReLU f32 out (64 MB)
// ---------------------------------------------------------------------------
__global__ void k_apply(const unsigned short* __restrict__ ybf, float* __restrict__ out,
                        const float* __restrict__ cA, const float* __restrict__ cB) {
    size_t idx    = (size_t)blockIdx.x * 256 + threadIdx.x;
    size_t stride = (size_t)gridDim.x * 256;
    const size_t n8 = (size_t)kB * kOUT * kNL / 8;
    const u16x8* yp = (const u16x8*)ybf;
    float4* op = (float4*)out;
    for (size_t i = idx; i < n8; i += stride) {
        int o = (int)((i >> 9) & 255);   // 512 u16x8 per (b,o) row
        float a = cA[o], c = cB[o];
        u16x8 v = yp[i];
        float4 r0, r1;
        r0.x = fmaxf(fmaf(a, bf2f(v[0]), c), 0.0f);
        r0.y = fmaxf(fmaf(a, bf2f(v[1]), c), 0.0f);
        r0.z = fmaxf(fmaf(a, bf2f(v[2]), c), 0.0f);
        r0.w = fmaxf(fmaf(a, bf2f(v[3]), c), 0.0f);
        r1.x = fmaxf(fmaf(a, bf2f(v[4]), c), 0.0f);
        r1.y = fmaxf(fmaf(a, bf2f(v[5]), c), 0.0f);
        r1.z = fmaxf(fmaf(a, bf2f(v[6]), c), 0.0f);
        r1.w = fmaxf(fmaf(a, bf2f(v[7]), c), 0.0f);
        op[2 * i]     = r0;
        op[2 * i + 1] = r1;
    }
}

// ---------------------------------------------------------------------------
extern "C" void kernel_launch(void* const* d_in, const int* in_sizes, int n_in,
                              void* d_out, int out_size, void* d_ws, size_t ws_size,
                              hipStream_t stream) {
    const float* xyzl  = (const float*)d_in[0];
    const float* xyzh  = (const float*)d_in[1];
    const float* flow  = (const float*)d_in[2];
    const float* fhigh = (const float*)d_in[3];
    const float* W     = (const float*)d_in[4];
    const float* bias  = (const float*)d_in[5];
    const float* gamma = (const float*)d_in[6];
    const float* beta  = (const float*)d_in[7];
    float* out = (float*)d_out;
    char*  ws  = (char*)d_ws;
    (void)in_sizes; (void)n_in; (void)out_size; (void)ws_size;

    // ws layout (bytes), total ~46 MB
    float*          w3   = (float*)(ws + 0);                   // 786432
    int*            idx3 = (int*)  (ws + 786432);              // 786432
    unsigned short* gtb  = (unsigned short*)(ws + 1572864);    // 8 MB (bf16, permuted)
    unsigned short* ybf  = (unsigned short*)(ws + 9961472);    // 32 MB (bf16 y)
    unsigned short* w1   = (unsigned short*)(ws + 43515904);   // 128 KB
    unsigned short* w2   = (unsigned short*)(ws + 43646976);   // 64 KB
    float*          ps   = (float*)(ws + 43712512);            // 1 MB
    float*          pq   = (float*)(ws + 44761088);            // 1 MB
    float*          cA   = (float*)(ws + 45809664);            // 1 KB
    float*          cB   = (float*)(ws + 45810688);            // 1 KB
    float4*         cand = (float4*)(ws + 45811712);           // 256 KB

    hipLaunchKernelGGL(k_prep_w,    dim3(256),          dim3(384), 0, stream, W, w1, w2);
    hipLaunchKernelGGL(k_prep_cand, dim3(kB),           dim3(256), 0, stream, xyzh, cand);
    hipLaunchKernelGGL(k_mega,      dim3(1280),         dim3(256), 0, stream,
                       fhigh, w1, gtb, xyzl, cand, w3, idx3);
    hipLaunchKernelGGL(k_gemm2,     dim3(kNL / 64, kB), dim3(256), 0, stream,
                       flow, w2, gtb, bias, w3, idx3, ybf, ps, pq);
    hipLaunchKernelGGL(k_finalize,  dim3(256),          dim3(256), 0, stream, ps, pq, gamma, beta, cA, cB);
    hipLaunchKernelGGL(k_apply,     dim3(2048),         dim3(256), 0, stream, ybf, out, cA, cB);
}

// Round 10
// 105.349 us; speedup vs baseline: 1.4608x; 1.1549x over previous
//
#include <hip/hip_runtime.h>
#include <math.h>

constexpr int kB   = 16;
constexpr int kNL  = 4096;
constexpr int kNH  = 1024;
constexpr int kCL  = 128;
constexpr int kCH  = 256;
constexpr int kOUT = 256;

typedef __attribute__((ext_vector_type(8))) short s16x8;
typedef __attribute__((ext_vector_type(8))) unsigned short u16x8;
typedef __attribute__((ext_vector_type(4))) unsigned short u16x4;
typedef __attribute__((ext_vector_type(4))) float f32x4;

__device__ __forceinline__ unsigned short f2bf(float x) {
    unsigned int u = __float_as_uint(x);
    return (unsigned short)((u + 0x7FFFu + ((u >> 16) & 1u)) >> 16);
}
__device__ __forceinline__ unsigned int f2bf_pk(float a, float b) {
    return (unsigned int)f2bf(a) | ((unsigned int)f2bf(b) << 16);
}
__device__ __forceinline__ float bf2f(unsigned short h) {
    return __uint_as_float((unsigned int)h << 16);
}

// ---------------------------------------------------------------------------
// Merged prep: blocks 0..255 convert W rows; blocks 256..271 build cand[b].
// cand[b][j] = {2x, 2y, 2z, x^2+y^2+z^2}; pre-doubling is fp-exact.
// ---------------------------------------------------------------------------
__global__ void k_prep(const float* __restrict__ W, unsigned short* __restrict__ w1,
                       unsigned short* __restrict__ w2,
                       const float* __restrict__ xyzh, float4* __restrict__ cand) {
    if (blockIdx.x < 256) {
        int o = blockIdx.x, k = threadIdx.x;
        float v = W[o * 384 + k];
        if (k < kCH) w1[o * kCH + k] = f2bf(v);
        else         w2[o * kCL + (k - kCH)] = f2bf(v);
    } else {
        int b = blockIdx.x - 256;
        const float* H = xyzh + (size_t)b * kNH * 3;
        for (int j = threadIdx.x; j < kNH; j += 384) {
            float xx = H[j * 3 + 0], yy = H[j * 3 + 1], zz = H[j * 3 + 2];
            float s = __fmul_rn(xx, xx);
            s = __fadd_rn(s, __fmul_rn(yy, yy));
            s = __fadd_rn(s, __fmul_rn(zz, zz));
            cand[(size_t)b * kNH + j] = make_float4(xx + xx, yy + yy, zz + zz, s);
        }
    }
}

// ---------------------------------------------------------------------------
// GEMM1: G = W1 x feat_high per batch, 64-col tiles (proven round-6 version).
// Reads fhigh f32 directly, converts to bf16 while staging into LDS.
// Output gtb bf16 in fragment-permuted layout [w][hi][mi][r].
// ---------------------------------------------------------------------------
__global__ __launch_bounds__(256, 4) void k_gemm1(
    const float* __restrict__ fhigh, const unsigned short* __restrict__ w1,
    unsigned short* __restrict__ gtb)
{
    __shared__ __align__(16) unsigned short Bt[64][264];
    int b = blockIdx.y, j0 = blockIdx.x * 64, t = threadIdx.x;
    const float* src = fhigh + (size_t)b * kCH * kNH + j0;
    #pragma unroll
    for (int i = 0; i < 8; ++i) {
        int e = t + i * 256, cp = e >> 4, j4 = e & 15;
        f32x4 a  = *(const f32x4*)(src + (size_t)(2 * cp)     * kNH + 4 * j4);
        f32x4 b2 = *(const f32x4*)(src + (size_t)(2 * cp + 1) * kNH + 4 * j4);
        #pragma unroll
        for (int r = 0; r < 4; ++r)
            *(unsigned int*)(&Bt[4 * j4 + r][2 * cp]) = f2bf_pk(a[r], b2[r]);
    }
    __syncthreads();

    int w = t >> 6, lane = t & 63, lo = lane & 15, hi = lane >> 4;
    f32x4 vz = {0.f, 0.f, 0.f, 0.f};
    f32x4 acc[4][4];
    #pragma unroll
    for (int mi = 0; mi < 4; ++mi)
        #pragma unroll
        for (int ni = 0; ni < 4; ++ni) acc[mi][ni] = vz;

    #pragma unroll
    for (int ks = 0; ks < 8; ++ks) {
        s16x8 av[4], bv[4];
        #pragma unroll
        for (int mi = 0; mi < 4; ++mi)
            av[mi] = *(const s16x8*)(w1 + (size_t)(64 * w + 16 * mi + lo) * kCH + ks * 32 + hi * 8);
        #pragma unroll
        for (int ni = 0; ni < 4; ++ni)
            bv[ni] = *(const s16x8*)(&Bt[16 * ni + lo][ks * 32 + hi * 8]);
        #pragma unroll
        for (int mi = 0; mi < 4; ++mi)
            #pragma unroll
            for (int ni = 0; ni < 4; ++ni)
                acc[mi][ni] = __builtin_amdgcn_mfma_f32_16x16x32_bf16(av[mi], bv[ni], acc[mi][ni], 0, 0, 0);
    }

    unsigned short* G = gtb + ((size_t)b * kNH + j0) * kOUT;
    #pragma unroll
    for (int mi = 0; mi < 4; ++mi)
        #pragma unroll
        for (int ni = 0; ni < 4; ++ni) {
            f32x4 a = acc[mi][ni];
            u16x4 h;
            #pragma unroll
            for (int r = 0; r < 4; ++r) h[r] = f2bf(a[r]);
            *(u16x4*)(&G[(size_t)(16 * ni + lo) * kOUT + w * 64 + hi * 16 + mi * 4]) = h;
        }
}

// ---------------------------------------------------------------------------
// FUSED: three_nn + GEMM2 + interp-gather + bias + partial BN stats.
// T14 async-stage: flow loads issued at entry, converted to 16 packed-bf16
// regs; the LDS write + barrier happen AFTER the nn scan, so the VALU wall
// covers the load latency and no stage-barrier precedes it.
// ---------------------------------------------------------------------------
__global__ __launch_bounds__(256, 4) void k_gemm2(
    const float* __restrict__ flow, const unsigned short* __restrict__ w2,
    const unsigned short* __restrict__ gtb, const float* __restrict__ bias,
    const float* __restrict__ xyzl, const float4* __restrict__ cand,
    unsigned short* __restrict__ ybf, float* __restrict__ ps, float* __restrict__ pq)
{
    __shared__ __align__(16) char smem[17408];             // union: Bt | red
    unsigned short (*Bt)[136] = (unsigned short (*)[136])smem;
    float* red = (float*)smem;                             // [256][17]
    __shared__ float wc[64][3];
    __shared__ int   ic[64][3];
    __shared__ float md[64][4][3];
    __shared__ int   midx[64][4][3];

    int b = blockIdx.y, n0 = blockIdx.x * 64, t = threadIdx.x;
    int blin = b * gridDim.x + blockIdx.x;                 // 0..1023

    // --- T14: issue flow loads now, pack to bf16 regs (16 u32) ---
    const float* src = flow + (size_t)b * kCL * kNL + n0;
    unsigned int pk[16];
    #pragma unroll
    for (int i = 0; i < 4; ++i) {
        int e = t + i * 256, cp = e >> 4, n4 = e & 15;
        f32x4 a  = *(const f32x4*)(src + (size_t)(2 * cp)     * kNL + 4 * n4);
        f32x4 b2 = *(const f32x4*)(src + (size_t)(2 * cp + 1) * kNL + 4 * n4);
        #pragma unroll
        for (int r = 0; r < 4; ++r)
            pk[i * 4 + r] = f2bf_pk(a[r], b2[r]);
    }

    // --- nn-scan: 64 points, 4 j-subranges (wave-uniform), 2 ILP streams ---
    {
        int sub = t >> 6, ll = t & 63;
        int l = n0 + ll;
        const float* L = xyzl + ((size_t)b * kNL + l) * 3;
        float x = L[0], y = L[1], z = L[2];
        float sql = __fmul_rn(x, x);
        sql = __fadd_rn(sql, __fmul_rn(y, y));
        sql = __fadd_rn(sql, __fmul_rn(z, z));

        float dA0 = 1e30f, dA1 = 1e30f, dA2 = 1e30f;
        int   iA0 = 0,     iA1 = 0,     iA2 = 0;
        float dB0 = 1e30f, dB1 = 1e30f, dB2 = 1e30f;
        int   iB0 = 0,     iB1 = 0,     iB2 = 0;

        int jbeg = __builtin_amdgcn_readfirstlane(sub << 8);   // 256 cands/sub
        const float4* C = cand + ((size_t)b << 10) + jbeg;

        #pragma unroll 4
        for (int jj = 0; jj < 128; ++jj) {
            {   // stream A: [jbeg, jbeg+128)
                float4 c = C[jj];
                float inner2 = __fmul_rn(x, c.x);
                inner2 = __fadd_rn(inner2, __fmul_rn(y, c.y));
                inner2 = __fadd_rn(inner2, __fmul_rn(z, c.z));
                float dsq = __fsub_rn(__fadd_rn(sql, c.w), inner2);
                dsq = fmaxf(dsq, 0.0f);
                int j = jbeg + jj;
                bool c0 = dsq < dA0, c1 = dsq < dA1, c2 = dsq < dA2;
                float td = c1 ? dA1 : dsq;  int ti = c1 ? iA1 : j;
                dA2 = c2 ? td : dA2;        iA2 = c2 ? ti : iA2;
                td = c0 ? dA0 : dsq;        ti = c0 ? iA0 : j;
                dA1 = c1 ? td : dA1;        iA1 = c1 ? ti : iA1;
                dA0 = c0 ? dsq : dA0;       iA0 = c0 ? j : iA0;
            }
            {   // stream B: [jbeg+128, jbeg+256)
                float4 c = C[128 + jj];
                float inner2 = __fmul_rn(x, c.x);
                inner2 = __fadd_rn(inner2, __fmul_rn(y, c.y));
                inner2 = __fadd_rn(inner2, __fmul_rn(z, c.z));
                float dsq = __fsub_rn(__fadd_rn(sql, c.w), inner2);
                dsq = fmaxf(dsq, 0.0f);
                int j = jbeg + 128 + jj;
                bool c0 = dsq < dB0, c1 = dsq < dB1, c2 = dsq < dB2;
                float td = c1 ? dB1 : dsq;  int ti = c1 ? iB1 : j;
                dB2 = c2 ? td : dB2;        iB2 = c2 ? ti : iB2;
                td = c0 ? dB0 : dsq;        ti = c0 ? iB0 : j;
                dB1 = c1 ? td : dB1;        iB1 = c1 ? ti : iB1;
                dB0 = c0 ? dsq : dB0;       iB0 = c0 ? j : iB0;
            }
        }

        // merge stream B into A, lex (d, idx) = top_k tie semantics
        #pragma unroll
        for (int m = 0; m < 3; ++m) {
            float d = (m == 0) ? dB0 : (m == 1) ? dB1 : dB2;
            int  ii = (m == 0) ? iB0 : (m == 1) ? iB1 : iB2;
            bool lt2 = (d < dA2) || (d == dA2 && ii < iA2);
            if (lt2) {
                bool lt0 = (d < dA0) || (d == dA0 && ii < iA0);
                bool lt1 = (d < dA1) || (d == dA1 && ii < iA1);
                if (lt0)      { dA2 = dA1; iA2 = iA1; dA1 = dA0; iA1 = iA0; dA0 = d; iA0 = ii; }
                else if (lt1) { dA2 = dA1; iA2 = iA1; dA1 = d; iA1 = ii; }
                else          { dA2 = d; iA2 = ii; }
            }
        }

        md[ll][sub][0] = dA0;  md[ll][sub][1] = dA1;  md[ll][sub][2] = dA2;
        midx[ll][sub][0] = iA0; midx[ll][sub][1] = iA1; midx[ll][sub][2] = iA2;
        __syncthreads();

        if (sub == 0) {
            float e0 = 1e30f, e1 = 1e30f, e2 = 1e30f;
            int   a0 = 0x7fffffff, a1 = 0x7fffffff, a2 = 0x7fffffff;
            #pragma unroll
            for (int s = 0; s < 4; ++s) {
                #pragma unroll
                for (int k = 0; k < 3; ++k) {
                    float d = md[ll][s][k]; int ii = midx[ll][s][k];
                    bool lt2 = (d < e2) || (d == e2 && ii < a2);
                    if (lt2) {
                        bool lt0 = (d < e0) || (d == e0 && ii < a0);
                        bool lt1 = (d < e1) || (d == e1 && ii < a1);
                        if (lt0)      { e2 = e1; a2 = a1; e1 = e0; a1 = a0; e0 = d; a0 = ii; }
                        else if (lt1) { e2 = e1; a2 = a1; e1 = d; a1 = ii; }
                        else          { e2 = d; a2 = ii; }
                    }
                }
            }
            float q0 = fmaxf(sqrtf(e0), 1e-8f);
            float q1 = fmaxf(sqrtf(e1), 1e-8f);
            float q2 = fmaxf(sqrtf(e2), 1e-8f);
            float r0 = 1.0f / q0, r1 = 1.0f / q1, r2 = 1.0f / q2;
            float s = __fadd_rn(__fadd_rn(r0, r1), r2);
            wc[ll][0] = r0 / s;  wc[ll][1] = r1 / s;  wc[ll][2] = r2 / s;
            ic[ll][0] = a0;      ic[ll][1] = a1;      ic[ll][2] = a2;
        }
    }

    // --- write staged tile to LDS (loads completed long ago) ---
    #pragma unroll
    for (int i = 0; i < 4; ++i) {
        int e = t + i * 256, cp = e >> 4, n4 = e & 15;
        #pragma unroll
        for (int r = 0; r < 4; ++r)
            *(unsigned int*)(&Bt[4 * n4 + r][2 * cp]) = pk[i * 4 + r];
    }
    __syncthreads();   // Bt ready + wc/ic visible

    int w = t >> 6, lane = t & 63, lo = lane & 15, hi = lane >> 4;
    f32x4 vz = {0.f, 0.f, 0.f, 0.f};
    f32x4 acc[4][4];
    #pragma unroll
    for (int mi = 0; mi < 4; ++mi)
        #pragma unroll
        for (int ni = 0; ni < 4; ++ni) acc[mi][ni] = vz;

    // --- MFMA K-loop: y += W2 x feat_low_tile ---
    #pragma unroll
    for (int ks = 0; ks < 4; ++ks) {
        s16x8 av[4], bv[4];
        #pragma unroll
        for (int mi = 0; mi < 4; ++mi)
            av[mi] = *(const s16x8*)(w2 + (size_t)(64 * w + 16 * mi + lo) * kCL + ks * 32 + hi * 8);
        #pragma unroll
        for (int ni = 0; ni < 4; ++ni)
            bv[ni] = *(const s16x8*)(&Bt[16 * ni + lo][ks * 32 + hi * 8]);
        #pragma unroll
        for (int mi = 0; mi < 4; ++mi)
            #pragma unroll
            for (int ni = 0; ni < 4; ++ni)
                acc[mi][ni] = __builtin_amdgcn_mfma_f32_16x16x32_bf16(av[mi], bv[ni], acc[mi][ni], 0, 0, 0);
    }

    // --- gather: per neighbor k, stage 8 loads in registers, then FMA ---
    const unsigned short* Gb = gtb + (size_t)b * kNH * kOUT + w * 64 + hi * 16;
    #pragma unroll
    for (int k = 0; k < 3; ++k) {
        u16x8 g0[4], g1[4];
        float wcr[4];
        #pragma unroll
        for (int ni = 0; ni < 4; ++ni) {
            int lc = 16 * ni + lo;
            int jj = ic[lc][k];
            wcr[ni] = wc[lc][k];
            const u16x8* p = (const u16x8*)(Gb + (size_t)jj * kOUT);
            g0[ni] = p[0];
            g1[ni] = p[1];
        }
        #pragma unroll
        for (int ni = 0; ni < 4; ++ni) {
            float wg = wcr[ni];
            #pragma unroll
            for (int r = 0; r < 4; ++r) {
                acc[0][ni][r] = fmaf(wg, bf2f(g0[ni][r]),     acc[0][ni][r]);
                acc[1][ni][r] = fmaf(wg, bf2f(g0[ni][4 + r]), acc[1][ni][r]);
                acc[2][ni][r] = fmaf(wg, bf2f(g1[ni][r]),     acc[2][ni][r]);
                acc[3][ni][r] = fmaf(wg, bf2f(g1[ni][4 + r]), acc[3][ni][r]);
            }
        }
    }
    #pragma unroll
    for (int mi = 0; mi < 4; ++mi) {
        f32x4 bb = *(const f32x4*)(bias + 64 * w + 16 * mi + 4 * hi);
        #pragma unroll
        for (int ni = 0; ni < 4; ++ni) acc[mi][ni] += bb;
    }

    // store y (bf16)
    unsigned short* Y = ybf + (size_t)b * kOUT * kNL + n0;
    #pragma unroll
    for (int mi = 0; mi < 4; ++mi)
        #pragma unroll
        for (int ni = 0; ni < 4; ++ni)
            #pragma unroll
            for (int r = 0; r < 4; ++r)
                Y[(size_t)(64 * w + 16 * mi + 4 * hi + r) * kNL + 16 * ni + lo] = f2bf(acc[mi][ni][r]);

    // fused partial BN stats (from f32 accs), two rounds through red table
    int ow = t >> 6, omi = (t >> 4) & 3, ohi = (t >> 2) & 3, orr = t & 3;
    __syncthreads();   // Bt dead -> red
    #pragma unroll
    for (int mi = 0; mi < 4; ++mi) {
        f32x4 s = acc[mi][0] + acc[mi][1] + acc[mi][2] + acc[mi][3];
        #pragma unroll
        for (int r = 0; r < 4; ++r) red[t * 17 + mi * 4 + r] = s[r];
    }
    __syncthreads();
    float ssum = 0.0f;
    #pragma unroll
    for (int l2 = 0; l2 < 16; ++l2)
        ssum += red[(ow * 64 + ohi * 16 + l2) * 17 + omi * 4 + orr];
    __syncthreads();
    #pragma unroll
    for (int mi = 0; mi < 4; ++mi) {
        f32x4 q = acc[mi][0] * acc[mi][0] + acc[mi][1] * acc[mi][1]
                + acc[mi][2] * acc[mi][2] + acc[mi][3] * acc[mi][3];
        #pragma unroll
        for (int r = 0; r < 4; ++r) red[t * 17 + mi * 4 + r] = q[r];
    }
    __syncthreads();
    float qsum = 0.0f;
    #pragma unroll
    for (int l2 = 0; l2 < 16; ++l2)
        qsum += red[(ow * 64 + ohi * 16 + l2) * 17 + omi * 4 + orr];

    ps[(size_t)t * 1024 + blin] = ssum;
    pq[(size_t)t * 1024 + blin] = qsum;
}

// ---------------------------------------------------------------------------
__global__ void k_finalize(const float* __restrict__ ps, const float* __restrict__ pq,
                           const float* __restrict__ gamma, const float* __restrict__ beta,
                           float* __restrict__ cA, float* __restrict__ cB) {
    int o = blockIdx.x, t = threadIdx.x;
    float s = 0.0f, q = 0.0f;
    #pragma unroll
    for (int i = 0; i < 4; ++i) {
        s += ps[(size_t)o * 1024 + t + i * 256];
        q += pq[(size_t)o * 1024 + t + i * 256];
    }
    #pragma unroll
    for (int off = 32; off > 0; off >>= 1) {
        s += __shfl_down(s, off);
        q += __shfl_down(q, off);
    }
    __shared__ float ls[4], lq[4];
    if ((t & 63) == 0) { ls[t >> 6] = s; lq[t >> 6] = q; }
    __syncthreads();
    if (t == 0) {
        s = ls[0] + ls[1] + ls[2] + ls[3];
        q = lq[0] + lq[1] + lq[2] + lq[3];
        const float inv = 1.0f / (float)(kB * kNL);
        float mean = s * inv;
        float var  = q * inv - mean * mean;
        float a = gamma[o] * rsqrtf(var + 1e-5f);
        cA[o] = a;
        cB[o] = beta[o] - mean * a;
    }
}

// ---------------------------------------------------------------------------
// apply: read bf16 y (32 MB), write normalized+ReLU f32 out (64 MB)
// ---------------------------------------------------------------------------
__global__ void k_apply(const unsigned short* __restrict__ ybf, float* __restrict__ out,
                        const float* __restrict__ cA, const float* __restrict__ cB) {
    size_t idx    = (size_t)blockIdx.x * 256 + threadIdx.x;
    size_t stride = (size_t)gridDim.x * 256;
    const size_t n8 = (size_t)kB * kOUT * kNL / 8;
    const u16x8* yp = (const u16x8*)ybf;
    float4* op = (float4*)out;
    for (size_t i = idx; i < n8; i += stride) {
        int o = (int)((i >> 9) & 255);   // 512 u16x8 per (b,o) row
        float a = cA[o], c = cB[o];
        u16x8 v = yp[i];
        float4 r0, r1;
        r0.x = fmaxf(fmaf(a, bf2f(v[0]), c), 0.0f);
        r0.y = fmaxf(fmaf(a, bf2f(v[1]), c), 0.0f);
        r0.z = fmaxf(fmaf(a, bf2f(v[2]), c), 0.0f);
        r0.w = fmaxf(fmaf(a, bf2f(v[3]), c), 0.0f);
        r1.x = fmaxf(fmaf(a, bf2f(v[4]), c), 0.0f);
        r1.y = fmaxf(fmaf(a, bf2f(v[5]), c), 0.0f);
        r1.z = fmaxf(fmaf(a, bf2f(v[6]), c), 0.0f);
        r1.w = fmaxf(fmaf(a, bf2f(v[7]), c), 0.0f);
        op[2 * i]     = r0;
        op[2 * i + 1] = r1;
    }
}

// ---------------------------------------------------------------------------
extern "C" void kernel_launch(void* const* d_in, const int* in_sizes, int n_in,
                              void* d_out, int out_size, void* d_ws, size_t ws_size,
                              hipStream_t stream) {
    const float* xyzl  = (const float*)d_in[0];
    const float* xyzh  = (const float*)d_in[1];
    const float* flow  = (const float*)d_in[2];
    const float* fhigh = (const float*)d_in[3];
    const float* W     = (const float*)d_in[4];
    const float* bias  = (const float*)d_in[5];
    const float* gamma = (const float*)d_in[6];
    const float* beta  = (const float*)d_in[7];
    float* out = (float*)d_out;
    char*  ws  = (char*)d_ws;
    (void)in_sizes; (void)n_in; (void)out_size; (void)ws_size;

    // ws layout (bytes), total ~44.5 MB
    unsigned short* gtb  = (unsigned short*)(ws + 0);          // 8 MB (bf16, permuted)
    unsigned short* ybf  = (unsigned short*)(ws + 8388608);    // 32 MB (bf16 y)
    unsigned short* w1   = (unsigned short*)(ws + 41943040);   // 128 KB
    unsigned short* w2   = (unsigned short*)(ws + 42074112);   // 64 KB
    float*          ps   = (float*)(ws + 42139648);            // 1 MB
    float*          pq   = (float*)(ws + 43188224);            // 1 MB
    float*          cA   = (float*)(ws + 44236800);            // 1 KB
    float*          cB   = (float*)(ws + 44237824);            // 1 KB
    float4*         cand = (float4*)(ws + 44238848);           // 256 KB

    hipLaunchKernelGGL(k_prep,      dim3(272),          dim3(384), 0, stream,
                       W, w1, w2, xyzh, cand);
    hipLaunchKernelGGL(k_gemm1,     dim3(kNH / 64, kB), dim3(256), 0, stream, fhigh, w1, gtb);
    hipLaunchKernelGGL(k_gemm2,     dim3(kNL / 64, kB), dim3(256), 0, stream,
                       flow, w2, gtb, bias, xyzl, cand, ybf, ps, pq);
    hipLaunchKernelGGL(k_finalize,  dim3(256),          dim3(256), 0, stream, ps, pq, gamma, beta, cA, cB);
    hipLaunchKernelGGL(k_apply,     dim3(2048),         dim3(256), 0, stream, ybf, out, cA, cB);
}

// Round 11
// 102.075 us; speedup vs baseline: 1.5077x; 1.0321x over previous
//
#include <hip/hip_runtime.h>
#include <math.h>

constexpr int kB   = 16;
constexpr int kNL  = 4096;
constexpr int kNH  = 1024;
constexpr int kCL  = 128;
constexpr int kCH  = 256;
constexpr int kOUT = 256;

typedef __attribute__((ext_vector_type(8))) short s16x8;
typedef __attribute__((ext_vector_type(8))) unsigned short u16x8;
typedef __attribute__((ext_vector_type(4))) unsigned short u16x4;
typedef __attribute__((ext_vector_type(4))) float f32x4;

__device__ __forceinline__ unsigned short f2bf(float x) {
    unsigned int u = __float_as_uint(x);
    return (unsigned short)((u + 0x7FFFu + ((u >> 16) & 1u)) >> 16);
}
__device__ __forceinline__ unsigned int f2bf_pk(float a, float b) {
    return (unsigned int)f2bf(a) | ((unsigned int)f2bf(b) << 16);
}
__device__ __forceinline__ float bf2f(unsigned short h) {
    return __uint_as_float((unsigned int)h << 16);
}

// ---------------------------------------------------------------------------
// Merged prep: blocks 0..255 convert W rows; blocks 256..271 build cand[b].
// cand[b][j] = {2x, 2y, 2z, x^2+y^2+z^2}; pre-doubling is fp-exact.
// ---------------------------------------------------------------------------
__global__ void k_prep(const float* __restrict__ W, unsigned short* __restrict__ w1,
                       unsigned short* __restrict__ w2,
                       const float* __restrict__ xyzh, float4* __restrict__ cand) {
    if (blockIdx.x < 256) {
        int o = blockIdx.x, k = threadIdx.x;
        float v = W[o * 384 + k];
        if (k < kCH) w1[o * kCH + k] = f2bf(v);
        else         w2[o * kCL + (k - kCH)] = f2bf(v);
    } else {
        int b = blockIdx.x - 256;
        const float* H = xyzh + (size_t)b * kNH * 3;
        for (int j = threadIdx.x; j < kNH; j += 384) {
            float xx = H[j * 3 + 0], yy = H[j * 3 + 1], zz = H[j * 3 + 2];
            float s = __fmul_rn(xx, xx);
            s = __fadd_rn(s, __fmul_rn(yy, yy));
            s = __fadd_rn(s, __fmul_rn(zz, zz));
            cand[(size_t)b * kNH + j] = make_float4(xx + xx, yy + yy, zz + zz, s);
        }
    }
}

// ---------------------------------------------------------------------------
// GEMM1: G = W1 x feat_high per batch, 64-col tiles (proven round-6 version).
// ---------------------------------------------------------------------------
__global__ __launch_bounds__(256, 4) void k_gemm1(
    const float* __restrict__ fhigh, const unsigned short* __restrict__ w1,
    unsigned short* __restrict__ gtb)
{
    __shared__ __align__(16) unsigned short Bt[64][264];
    int b = blockIdx.y, j0 = blockIdx.x * 64, t = threadIdx.x;
    const float* src = fhigh + (size_t)b * kCH * kNH + j0;
    #pragma unroll
    for (int i = 0; i < 8; ++i) {
        int e = t + i * 256, cp = e >> 4, j4 = e & 15;
        f32x4 a  = *(const f32x4*)(src + (size_t)(2 * cp)     * kNH + 4 * j4);
        f32x4 b2 = *(const f32x4*)(src + (size_t)(2 * cp + 1) * kNH + 4 * j4);
        #pragma unroll
        for (int r = 0; r < 4; ++r)
            *(unsigned int*)(&Bt[4 * j4 + r][2 * cp]) = f2bf_pk(a[r], b2[r]);
    }
    __syncthreads();

    int w = t >> 6, lane = t & 63, lo = lane & 15, hi = lane >> 4;
    f32x4 vz = {0.f, 0.f, 0.f, 0.f};
    f32x4 acc[4][4];
    #pragma unroll
    for (int mi = 0; mi < 4; ++mi)
        #pragma unroll
        for (int ni = 0; ni < 4; ++ni) acc[mi][ni] = vz;

    #pragma unroll
    for (int ks = 0; ks < 8; ++ks) {
        s16x8 av[4], bv[4];
        #pragma unroll
        for (int mi = 0; mi < 4; ++mi)
            av[mi] = *(const s16x8*)(w1 + (size_t)(64 * w + 16 * mi + lo) * kCH + ks * 32 + hi * 8);
        #pragma unroll
        for (int ni = 0; ni < 4; ++ni)
            bv[ni] = *(const s16x8*)(&Bt[16 * ni + lo][ks * 32 + hi * 8]);
        #pragma unroll
        for (int mi = 0; mi < 4; ++mi)
            #pragma unroll
            for (int ni = 0; ni < 4; ++ni)
                acc[mi][ni] = __builtin_amdgcn_mfma_f32_16x16x32_bf16(av[mi], bv[ni], acc[mi][ni], 0, 0, 0);
    }

    unsigned short* G = gtb + ((size_t)b * kNH + j0) * kOUT;
    #pragma unroll
    for (int mi = 0; mi < 4; ++mi)
        #pragma unroll
        for (int ni = 0; ni < 4; ++ni) {
            f32x4 a = acc[mi][ni];
            u16x4 h;
            #pragma unroll
            for (int r = 0; r < 4; ++r) h[r] = f2bf(a[r]);
            *(u16x4*)(&G[(size_t)(16 * ni + lo) * kOUT + w * 64 + hi * 16 + mi * 4]) = h;
        }
}

// ---------------------------------------------------------------------------
// FUSED: three_nn (LDS-broadcast candidates) + GEMM2 + gather + bias + stats.
// Candidate table staged in LDS: inner loop is ds_read_b128 at a wave-uniform
// address (HW broadcast, conflict-free, LDS pipe overlaps VALU) — removes the
// SMEM-latency stall that pinned the scan at ~47 us.
// LDS liveness: {cand, md, midx} (nn) -> {Bt} (kloop) -> {red} (stats),
// all unioned in one 22528-B region.
// ---------------------------------------------------------------------------
__global__ __launch_bounds__(256, 4) void k_gemm2(
    const float* __restrict__ flow, const unsigned short* __restrict__ w2,
    const unsigned short* __restrict__ gtb, const float* __restrict__ bias,
    const float* __restrict__ xyzl, const float4* __restrict__ cand,
    unsigned short* __restrict__ ybf, float* __restrict__ ps, float* __restrict__ pq)
{
    __shared__ __align__(16) char smem[22528];
    float4* cl  = (float4*)smem;                                 // [1024] (nn)
    float*  mdp = (float*)(smem + 16384);                        // [64][4][3] (nn)
    int*    mip = (int*)(smem + 19456);                          // [64][4][3] (nn)
    unsigned short (*Bt)[136] = (unsigned short (*)[136])smem;   // kloop
    float*  red = (float*)smem;                                  // [256][17] stats
    __shared__ float wc[64][3];
    __shared__ int   ic[64][3];

    int b = blockIdx.y, n0 = blockIdx.x * 64, t = threadIdx.x;
    int blin = b * gridDim.x + blockIdx.x;                       // 0..1023

    // --- stage candidate table into LDS (16 KB) ---
    const float4* Cg = cand + ((size_t)b << 10);
    #pragma unroll
    for (int i = 0; i < 4; ++i) cl[t + i * 256] = Cg[t + i * 256];
    __syncthreads();

    // --- nn-scan: 64 points, 4 j-subranges (wave-uniform), 2 ILP streams ---
    {
        int sub = t >> 6, ll = t & 63;
        int l = n0 + ll;
        const float* L = xyzl + ((size_t)b * kNL + l) * 3;
        float x = L[0], y = L[1], z = L[2];
        float sql = __fmul_rn(x, x);
        sql = __fadd_rn(sql, __fmul_rn(y, y));
        sql = __fadd_rn(sql, __fmul_rn(z, z));

        float dA0 = 1e30f, dA1 = 1e30f, dA2 = 1e30f;
        int   iA0 = 0,     iA1 = 0,     iA2 = 0;
        float dB0 = 1e30f, dB1 = 1e30f, dB2 = 1e30f;
        int   iB0 = 0,     iB1 = 0,     iB2 = 0;

        int jbeg = __builtin_amdgcn_readfirstlane(sub << 8);   // 256 cands/sub
        const float4* C = cl + jbeg;

        #pragma unroll 4
        for (int jj = 0; jj < 128; ++jj) {
            {   // stream A: [jbeg, jbeg+128)
                float4 c = C[jj];                 // ds_read_b128, broadcast
                float inner2 = __fmul_rn(x, c.x);
                inner2 = __fadd_rn(inner2, __fmul_rn(y, c.y));
                inner2 = __fadd_rn(inner2, __fmul_rn(z, c.z));
                float dsq = __fsub_rn(__fadd_rn(sql, c.w), inner2);
                dsq = fmaxf(dsq, 0.0f);
                int j = jbeg + jj;
                bool c0 = dsq < dA0, c1 = dsq < dA1, c2 = dsq < dA2;
                float td = c1 ? dA1 : dsq;  int ti = c1 ? iA1 : j;
                dA2 = c2 ? td : dA2;        iA2 = c2 ? ti : iA2;
                td = c0 ? dA0 : dsq;        ti = c0 ? iA0 : j;
                dA1 = c1 ? td : dA1;        iA1 = c1 ? ti : iA1;
                dA0 = c0 ? dsq : dA0;       iA0 = c0 ? j : iA0;
            }
            {   // stream B: [jbeg+128, jbeg+256)
                float4 c = C[128 + jj];
                float inner2 = __fmul_rn(x, c.x);
                inner2 = __fadd_rn(inner2, __fmul_rn(y, c.y));
                inner2 = __fadd_rn(inner2, __fmul_rn(z, c.z));
                float dsq = __fsub_rn(__fadd_rn(sql, c.w), inner2);
                dsq = fmaxf(dsq, 0.0f);
                int j = jbeg + 128 + jj;
                bool c0 = dsq < dB0, c1 = dsq < dB1, c2 = dsq < dB2;
                float td = c1 ? dB1 : dsq;  int ti = c1 ? iB1 : j;
                dB2 = c2 ? td : dB2;        iB2 = c2 ? ti : iB2;
                td = c0 ? dB0 : dsq;        ti = c0 ? iB0 : j;
                dB1 = c1 ? td : dB1;        iB1 = c1 ? ti : iB1;
                dB0 = c0 ? dsq : dB0;       iB0 = c0 ? j : iB0;
            }
        }

        // merge stream B into A, lex (d, idx) = top_k tie semantics
        #pragma unroll
        for (int m = 0; m < 3; ++m) {
            float d = (m == 0) ? dB0 : (m == 1) ? dB1 : dB2;
            int  ii = (m == 0) ? iB0 : (m == 1) ? iB1 : iB2;
            bool lt2 = (d < dA2) || (d == dA2 && ii < iA2);
            if (lt2) {
                bool lt0 = (d < dA0) || (d == dA0 && ii < iA0);
                bool lt1 = (d < dA1) || (d == dA1 && ii < iA1);
                if (lt0)      { dA2 = dA1; iA2 = iA1; dA1 = dA0; iA1 = iA0; dA0 = d; iA0 = ii; }
                else if (lt1) { dA2 = dA1; iA2 = iA1; dA1 = d; iA1 = ii; }
                else          { dA2 = d; iA2 = ii; }
            }
        }

        int mo = (ll * 4 + sub) * 3;
        mdp[mo + 0] = dA0;  mdp[mo + 1] = dA1;  mdp[mo + 2] = dA2;
        mip[mo + 0] = iA0;  mip[mo + 1] = iA1;  mip[mo + 2] = iA2;
        __syncthreads();

        if (sub == 0) {
            float e0 = 1e30f, e1 = 1e30f, e2 = 1e30f;
            int   a0 = 0x7fffffff, a1 = 0x7fffffff, a2 = 0x7fffffff;
            #pragma unroll
            for (int s = 0; s < 4; ++s) {
                #pragma unroll
                for (int k = 0; k < 3; ++k) {
                    float d = mdp[(ll * 4 + s) * 3 + k];
                    int  ii = mip[(ll * 4 + s) * 3 + k];
                    bool lt2 = (d < e2) || (d == e2 && ii < a2);
                    if (lt2) {
                        bool lt0 = (d < e0) || (d == e0 && ii < a0);
                        bool lt1 = (d < e1) || (d == e1 && ii < a1);
                        if (lt0)      { e2 = e1; a2 = a1; e1 = e0; a1 = a0; e0 = d; a0 = ii; }
                        else if (lt1) { e2 = e1; a2 = a1; e1 = d; a1 = ii; }
                        else          { e2 = d; a2 = ii; }
                    }
                }
            }
            float q0 = fmaxf(sqrtf(e0), 1e-8f);
            float q1 = fmaxf(sqrtf(e1), 1e-8f);
            float q2 = fmaxf(sqrtf(e2), 1e-8f);
            float r0 = 1.0f / q0, r1 = 1.0f / q1, r2 = 1.0f / q2;
            float s = __fadd_rn(__fadd_rn(r0, r1), r2);
            wc[ll][0] = r0 / s;  wc[ll][1] = r1 / s;  wc[ll][2] = r2 / s;
            ic[ll][0] = a0;      ic[ll][1] = a1;      ic[ll][2] = a2;
        }
    }
    __syncthreads();   // cand/md/midx dead; wc/ic visible

    // --- stage feat_low tile (f32 -> packed bf16) into Bt ---
    const float* src = flow + (size_t)b * kCL * kNL + n0;
    #pragma unroll
    for (int i = 0; i < 4; ++i) {
        int e = t + i * 256, cp = e >> 4, n4 = e & 15;
        f32x4 a  = *(const f32x4*)(src + (size_t)(2 * cp)     * kNL + 4 * n4);
        f32x4 b2 = *(const f32x4*)(src + (size_t)(2 * cp + 1) * kNL + 4 * n4);
        #pragma unroll
        for (int r = 0; r < 4; ++r)
            *(unsigned int*)(&Bt[4 * n4 + r][2 * cp]) = f2bf_pk(a[r], b2[r]);
    }
    __syncthreads();

    int w = t >> 6, lane = t & 63, lo = lane & 15, hi = lane >> 4;
    f32x4 vz = {0.f, 0.f, 0.f, 0.f};
    f32x4 acc[4][4];
    #pragma unroll
    for (int mi = 0; mi < 4; ++mi)
        #pragma unroll
        for (int ni = 0; ni < 4; ++ni) acc[mi][ni] = vz;

    // --- MFMA K-loop ---
    #pragma unroll
    for (int ks = 0; ks < 4; ++ks) {
        s16x8 av[4], bv[4];
        #pragma unroll
        for (int mi = 0; mi < 4; ++mi)
            av[mi] = *(const s16x8*)(w2 + (size_t)(64 * w + 16 * mi + lo) * kCL + ks * 32 + hi * 8);
        #pragma unroll
        for (int ni = 0; ni < 4; ++ni)
            bv[ni] = *(const s16x8*)(&Bt[16 * ni + lo][ks * 32 + hi * 8]);
        #pragma unroll
        for (int mi = 0; mi < 4; ++mi)
            #pragma unroll
            for (int ni = 0; ni < 4; ++ni)
                acc[mi][ni] = __builtin_amdgcn_mfma_f32_16x16x32_bf16(av[mi], bv[ni], acc[mi][ni], 0, 0, 0);
    }

    // --- gather: per neighbor k, stage 8 loads in registers, then FMA ---
    const unsigned short* Gb = gtb + (size_t)b * kNH * kOUT + w * 64 + hi * 16;
    #pragma unroll
    for (int k = 0; k < 3; ++k) {
        u16x8 g0[4], g1[4];
        float wcr[4];
        #pragma unroll
        for (int ni = 0; ni < 4; ++ni) {
            int lc = 16 * ni + lo;
            int jj = ic[lc][k];
            wcr[ni] = wc[lc][k];
            const u16x8* p = (const u16x8*)(Gb + (size_t)jj * kOUT);
            g0[ni] = p[0];
            g1[ni] = p[1];
        }
        #pragma unroll
        for (int ni = 0; ni < 4; ++ni) {
            float wg = wcr[ni];
            #pragma unroll
            for (int r = 0; r < 4; ++r) {
                acc[0][ni][r] = fmaf(wg, bf2f(g0[ni][r]),     acc[0][ni][r]);
                acc[1][ni][r] = fmaf(wg, bf2f(g0[ni][4 + r]), acc[1][ni][r]);
                acc[2][ni][r] = fmaf(wg, bf2f(g1[ni][r]),     acc[2][ni][r]);
                acc[3][ni][r] = fmaf(wg, bf2f(g1[ni][4 + r]), acc[3][ni][r]);
            }
        }
    }
    #pragma unroll
    for (int mi = 0; mi < 4; ++mi) {
        f32x4 bb = *(const f32x4*)(bias + 64 * w + 16 * mi + 4 * hi);
        #pragma unroll
        for (int ni = 0; ni < 4; ++ni) acc[mi][ni] += bb;
    }

    // store y (bf16)
    unsigned short* Y = ybf + (size_t)b * kOUT * kNL + n0;
    #pragma unroll
    for (int mi = 0; mi < 4; ++mi)
        #pragma unroll
        for (int ni = 0; ni < 4; ++ni)
            #pragma unroll
            for (int r = 0; r < 4; ++r)
                Y[(size_t)(64 * w + 16 * mi + 4 * hi + r) * kNL + 16 * ni + lo] = f2bf(acc[mi][ni][r]);

    // fused partial BN stats (from f32 accs), two rounds through red table
    int ow = t >> 6, omi = (t >> 4) & 3, ohi = (t >> 2) & 3, orr = t & 3;
    __syncthreads();   // Bt dead -> red
    #pragma unroll
    for (int mi = 0; mi < 4; ++mi) {
        f32x4 s = acc[mi][0] + acc[mi][1] + acc[mi][2] + acc[mi][3];
        #pragma unroll
        for (int r = 0; r < 4; ++r) red[t * 17 + mi * 4 + r] = s[r];
    }
    __syncthreads();
    float ssum = 0.0f;
    #pragma unroll
    for (int l2 = 0; l2 < 16; ++l2)
        ssum += red[(ow * 64 + ohi * 16 + l2) * 17 + omi * 4 + orr];
    __syncthreads();
    #pragma unroll
    for (int mi = 0; mi < 4; ++mi) {
        f32x4 q = acc[mi][0] * acc[mi][0] + acc[mi][1] * acc[mi][1]
                + acc[mi][2] * acc[mi][2] + acc[mi][3] * acc[mi][3];
        #pragma unroll
        for (int r = 0; r < 4; ++r) red[t * 17 + mi * 4 + r] = q[r];
    }
    __syncthreads();
    float qsum = 0.0f;
    #pragma unroll
    for (int l2 = 0; l2 < 16; ++l2)
        qsum += red[(ow * 64 + ohi * 16 + l2) * 17 + omi * 4 + orr];

    ps[(size_t)t * 1024 + blin] = ssum;
    pq[(size_t)t * 1024 + blin] = qsum;
}

// ---------------------------------------------------------------------------
__global__ void k_finalize(const float* __restrict__ ps, const float* __restrict__ pq,
                           const float* __restrict__ gamma, const float* __restrict__ beta,
                           float* __restrict__ cA, float* __restrict__ cB) {
    int o = blockIdx.x, t = threadIdx.x;
    float s = 0.0f, q = 0.0f;
    #pragma unroll
    for (int i = 0; i < 4; ++i) {
        s += ps[(size_t)o * 1024 + t + i * 256];
        q += pq[(size_t)o * 1024 + t + i * 256];
    }
    #pragma unroll
    for (int off = 32; off > 0; off >>= 1) {
        s += __shfl_down(s, off);
        q += __shfl_down(q, off);
    }
    __shared__ float ls[4], lq[4];
    if ((t & 63) == 0) { ls[t >> 6] = s; lq[t >> 6] = q; }
    __syncthreads();
    if (t == 0) {
        s = ls[0] + ls[1] + ls[2] + ls[3];
        q = lq[0] + lq[1] + lq[2] + lq[3];
        const float inv = 1.0f / (float)(kB * kNL);
        float mean = s * inv;
        float var  = q * inv - mean * mean;
        float a = gamma[o] * rsqrtf(var + 1e-5f);
        cA[o] = a;
        cB[o] = beta[o] - mean * a;
    }
}

// ---------------------------------------------------------------------------
// apply: read bf16 y (32 MB), write normalized+ReLU f32 out (64 MB)
// ---------------------------------------------------------------------------
__global__ void k_apply(const unsigned short* __restrict__ ybf, float* __restrict__ out,
                        const float* __restrict__ cA, const float* __restrict__ cB) {
    size_t idx    = (size_t)blockIdx.x * 256 + threadIdx.x;
    size_t stride = (size_t)gridDim.x * 256;
    const size_t n8 = (size_t)kB * kOUT * kNL / 8;
    const u16x8* yp = (const u16x8*)ybf;
    float4* op = (float4*)out;
    for (size_t i = idx; i < n8; i += stride) {
        int o = (int)((i >> 9) & 255);   // 512 u16x8 per (b,o) row
        float a = cA[o], c = cB[o];
        u16x8 v = yp[i];
        float4 r0, r1;
        r0.x = fmaxf(fmaf(a, bf2f(v[0]), c), 0.0f);
        r0.y = fmaxf(fmaf(a, bf2f(v[1]), c), 0.0f);
        r0.z = fmaxf(fmaf(a, bf2f(v[2]), c), 0.0f);
        r0.w = fmaxf(fmaf(a, bf2f(v[3]), c), 0.0f);
        r1.x = fmaxf(fmaf(a, bf2f(v[4]), c), 0.0f);
        r1.y = fmaxf(fmaf(a, bf2f(v[5]), c), 0.0f);
        r1.z = fmaxf(fmaf(a, bf2f(v[6]), c), 0.0f);
        r1.w = fmaxf(fmaf(a, bf2f(v[7]), c), 0.0f);
        op[2 * i]     = r0;
        op[2 * i + 1] = r1;
    }
}

// ---------------------------------------------------------------------------
extern "C" void kernel_launch(void* const* d_in, const int* in_sizes, int n_in,
                              void* d_out, int out_size, void* d_ws, size_t ws_size,
                              hipStream_t stream) {
    const float* xyzl  = (const float*)d_in[0];
    const float* xyzh  = (const float*)d_in[1];
    const float* flow  = (const float*)d_in[2];
    const float* fhigh = (const float*)d_in[3];
    const float* W     = (const float*)d_in[4];
    const float* bias  = (const float*)d_in[5];
    const float* gamma = (const float*)d_in[6];
    const float* beta  = (const float*)d_in[7];
    float* out = (float*)d_out;
    char*  ws  = (char*)d_ws;
    (void)in_sizes; (void)n_in; (void)out_size; (void)ws_size;

    // ws layout (bytes), total ~44.5 MB
    unsigned short* gtb  = (unsigned short*)(ws + 0);          // 8 MB (bf16, permuted)
    unsigned short* ybf  = (unsigned short*)(ws + 8388608);    // 32 MB (bf16 y)
    unsigned short* w1   = (unsigned short*)(ws + 41943040);   // 128 KB
    unsigned short* w2   = (unsigned short*)(ws + 42074112);   // 64 KB
    float*          ps   = (float*)(ws + 42139648);            // 1 MB
    float*          pq   = (float*)(ws + 43188224);            // 1 MB
    float*          cA   = (float*)(ws + 44236800);            // 1 KB
    float*          cB   = (float*)(ws + 44237824);            // 1 KB
    float4*         cand = (float4*)(ws + 44238848);           // 256 KB

    hipLaunchKernelGGL(k_prep,      dim3(272),          dim3(384), 0, stream,
                       W, w1, w2, xyzh, cand);
    hipLaunchKernelGGL(k_gemm1,     dim3(kNH / 64, kB), dim3(256), 0, stream, fhigh, w1, gtb);
    hipLaunchKernelGGL(k_gemm2,     dim3(kNL / 64, kB), dim3(256), 0, stream,
                       flow, w2, gtb, bias, xyzl, cand, ybf, ps, pq);
    hipLaunchKernelGGL(k_finalize,  dim3(256),          dim3(256), 0, stream, ps, pq, gamma, beta, cA, cB);
    hipLaunchKernelGGL(k_apply,     dim3(2048),         dim3(256), 0, stream, ybf, out, cA, cB);
}